// Round 11
// baseline (110.905 us; speedup 1.0000x reference)
//
#include <hip/hip_runtime.h>

#define NIMG 8
#define KCH 21
#define HW2 16384       // 128*128 input pixels
#define PD 4096         // 64*64 downsampled
#define NT 256          // 16-wide tiles per image
#define RT 8            // rowtiles per wave
#define NSEG 16         // q-segments (16 tiles each)
#define SQRT_LOG2E 1.2011224087864498f

typedef __attribute__((ext_vector_type(8))) short short8;   // 8 bf16 = 4 VGPR
typedef __attribute__((ext_vector_type(4))) float f32x4;

__device__ __forceinline__ unsigned short bf16rne(float x) {
    unsigned u = __float_as_uint(x);
    unsigned r = (u + 0x7FFFu + ((u >> 16) & 1u)) >> 16;
    return (unsigned short)r;
}
__device__ __forceinline__ float bf2f(unsigned short b) {
    return __uint_as_float(((unsigned)b) << 16);
}

// ---------------- fused prep ----------------
// blocks [0,2048): AB path, 2 pixels/thread, float4 coalesced loads.
// blocks [2048,2176): feat path, Gram operands with norm-offset slots:
//   GA: [hi(5)|hi(5)|lo(5)|lo(5)|nh_hi|nh_lo|1|1|0..]
//   GB: [hi(5)|lo(5)|hi(5)|lo(5)|1|1|nh_hi|nh_lo|0..]
//   => Gram MFMA output = f^p.f^q - hp - hq = log2(W_pq) directly.
// Block 0 thread 0 also zeroes out[0] for crf's atomicAdd.
__global__ __launch_bounds__(256)
void prep_kernel(const float* __restrict__ images,
                 const float* __restrict__ logS, const float* __restrict__ log1S,
                 const float* __restrict__ rois,
                 unsigned short* __restrict__ AopM, unsigned short* __restrict__ BopM,
                 unsigned short* __restrict__ GA, unsigned short* __restrict__ GB,
                 float* __restrict__ out)
{
    const int bid = blockIdx.x;
    if (bid == 0 && threadIdx.x == 0) out[0] = 0.0f;
    if (bid < 2048) {
        unsigned t = bid * 256 + threadIdx.x;   // 0..524287
        int h = t & 2047;
        int k = (t >> 11) & 31;
        int n = t >> 16;
        int p0 = h << 1;                        // even pixel
        size_t o = (size_t)((n * NT + (p0 >> 4)) * 4 + (k >> 3)) * 128
                 + (p0 & 15) * 8 + (k & 7);
        unsigned short a0 = 0, a1 = 0, b0 = 0, b1 = 0;
        if (k < KCH) {
            int i = p0 >> 6, j0 = p0 & 63;
            int base = (i << 8) + (j0 << 1);    // 16B-aligned (j0 even)
            int nk = n * KCH + k;
            const float* ls = logS  + (size_t)nk * HW2;
            const float* l1 = log1S + (size_t)nk * HW2;
            float4 lsa = *reinterpret_cast<const float4*>(ls + base);
            float4 lsb = *reinterpret_cast<const float4*>(ls + base + 128);
            float4 l1a = *reinterpret_cast<const float4*>(l1 + base);
            float4 l1b = *reinterpret_cast<const float4*>(l1 + base + 128);
            float4 rr  = *reinterpret_cast<const float4*>(rois + (size_t)n * HW2 + base);
            a0 = bf16rne(0.25f * (lsa.x + lsa.y + lsb.x + lsb.y) * rr.x);
            a1 = bf16rne(0.25f * (lsa.z + lsa.w + lsb.z + lsb.w) * rr.z);
            b0 = bf16rne(0.25f * (l1a.x + l1a.y + l1b.x + l1b.y) * rr.x);
            b1 = bf16rne(0.25f * (l1a.z + l1a.w + l1b.z + l1b.w) * rr.z);
        }
        AopM[o] = a0; AopM[o + 8] = a1;
        BopM[o] = b0; BopM[o + 8] = b1;
    } else {
        int t = (bid - 2048) * 256 + threadIdx.x;  // 0..32767
        int n = t >> 12, p = t & 4095;
        int i = p >> 6, j = p & 63;
        int base = (i << 8) + (j << 1);
        const float* img = images + (size_t)n * 3 * HW2;

        float f[5];
        f[0] = img[base]           * (SQRT_LOG2E / 15.0f);
        f[1] = img[HW2 + base]     * (SQRT_LOG2E / 15.0f);
        f[2] = img[2 * HW2 + base] * (SQRT_LOG2E / 15.0f);
        f[3] = (float)j * (SQRT_LOG2E / 50.0f);
        f[4] = (float)i * (SQRT_LOG2E / 50.0f);

        unsigned short hi[5], lo[5];
        float hsum = 0.0f;
#pragma unroll
        for (int c = 0; c < 5; ++c) {
            hi[c] = bf16rne(f[c]);
            float hf = bf2f(hi[c]);
            lo[c] = bf16rne(f[c] - hf);
            float fh = hf + bf2f(lo[c]);
            hsum = fmaf(fh, fh, hsum);
        }
        float nh = -0.5f * hsum;                 // -hp in log2 units
        unsigned short nhh = bf16rne(nh);
        unsigned short nhl = bf16rne(nh - bf2f(nhh));
        const unsigned short one = 0x3F80;       // bf16 1.0

        unsigned short av[32], bv[32];
#pragma unroll
        for (int s = 0; s < 32; ++s) { av[s] = 0; bv[s] = 0; }
#pragma unroll
        for (int c = 0; c < 5; ++c) {
            av[c]      = hi[c]; bv[c]      = hi[c];
            av[c + 5]  = hi[c]; bv[c + 5]  = lo[c];
            av[c + 10] = lo[c]; bv[c + 10] = hi[c];
            av[c + 15] = lo[c]; bv[c + 15] = lo[c];
        }
        av[20] = nhh; bv[20] = one;
        av[21] = nhl; bv[21] = one;
        av[22] = one; bv[22] = nhh;
        av[23] = one; bv[23] = nhl;

        int rt = p >> 4, m = p & 15;
        unsigned short* ga = GA + (size_t)(n * NT + rt) * 512 + m * 8;
        unsigned short* gb = GB + (size_t)(n * NT + rt) * 512 + m * 8;
#pragma unroll
        for (int g = 0; g < 4; ++g)
#pragma unroll
            for (int e2 = 0; e2 < 4; ++e2) {
                int s = g * 8 + e2 * 2;
                ushort2 pa; pa.x = av[s]; pa.y = av[s + 1];
                ushort2 pb; pb.x = bv[s]; pb.y = bv[s + 1];
                *reinterpret_cast<ushort2*>(ga + g * 128 + e2 * 2) = pa;
                *reinterpret_cast<ushort2*>(gb + g * 128 + e2 * 2) = pb;
            }
    }
}

// ---- crf: per-wave (8 rowtiles, 16-tile q-segment); Gram MFMA = log2W ------
__global__ __launch_bounds__(256)
void crf_kernel(const unsigned short* __restrict__ AopM,
                const unsigned short* __restrict__ BopM,
                const unsigned short* __restrict__ GA,
                const unsigned short* __restrict__ GB,
                float* __restrict__ out)
{
    const int tid = threadIdx.x;
    const int l = tid & 63;
    const int w = __builtin_amdgcn_readfirstlane(tid >> 6);
    const int unit = blockIdx.x * 4 + w;       // 0..4095
    const int n = unit >> 9;                   // 512 units per image
    const int rem = unit & 511;
    const int rt0 = (rem >> 4) << 3;           // 8 rowtiles per wave
    const int seg = rem & 15;
    const int lf = l * 8;

    short8 aM[RT], aG[RT];
#pragma unroll
    for (int i = 0; i < RT; ++i) {
        const size_t tb = (size_t)(n * NT + rt0 + i) * 512;
        aM[i] = *reinterpret_cast<const short8*>(AopM + tb + lf);
        aG[i] = *reinterpret_cast<const short8*>(GA   + tb + lf);
    }

    const int ct0 = seg * 16;
    const unsigned short* bMb = BopM + (size_t)(n * NT + ct0) * 512;  // uniform
    const unsigned short* bGb = GB   + (size_t)(n * NT + ct0) * 512;  // uniform

    const f32x4 zero = {0.0f, 0.0f, 0.0f, 0.0f};
    float acc[RT] = {};

    short8 bm = *reinterpret_cast<const short8*>(bMb + lf);
    short8 bg = *reinterpret_cast<const short8*>(bGb + lf);

#pragma unroll 4
    for (int tt = 0; tt < 16; ++tt) {
        const int nx = (tt + 1 < 16) ? tt + 1 : 15;   // clamped prefetch
        short8 bm_n = *reinterpret_cast<const short8*>(bMb + nx * 512 + lf);
        short8 bg_n = *reinterpret_cast<const short8*>(bGb + nx * 512 + lf);

#pragma unroll
        for (int i = 0; i < RT; ++i) {
            f32x4 mm = __builtin_amdgcn_mfma_f32_16x16x32_bf16(aM[i], bm, zero, 0, 0, 0);
            f32x4 gg = __builtin_amdgcn_mfma_f32_16x16x32_bf16(aG[i], bg, zero, 0, 0, 0);
#pragma unroll
            for (int r = 0; r < 4; ++r) {
                float wgt;
                asm("v_exp_f32 %0, %1" : "=v"(wgt) : "v"(gg[r]));  // W = 2^(log2W)
                acc[i] = fmaf(wgt, mm[r], acc[i]);
            }
        }
        bm = bm_n; bg = bg_n;
    }

    float partial = ((acc[0] + acc[1]) + (acc[2] + acc[3]))
                  + ((acc[4] + acc[5]) + (acc[6] + acc[7]));
#pragma unroll
    for (int off = 32; off; off >>= 1)
        partial += __shfl_down(partial, off, 64);

    __shared__ float sred[4];
    if (l == 0) sred[w] = partial;
    __syncthreads();
    if (tid == 0) {
        float s = (sred[0] + sred[1]) + (sred[2] + sred[3]);
        atomicAdd(out, s * (1e-9f / 8.0f));    // WEIGHT * sum / N, pre-scaled
    }
}

extern "C" void kernel_launch(void* const* d_in, const int* in_sizes, int n_in,
                              void* d_out, int out_size, void* d_ws, size_t ws_size,
                              hipStream_t stream)
{
    const float* images = (const float*)d_in[0];
    const float* logS   = (const float*)d_in[1];
    const float* log1S  = (const float*)d_in[2];
    const float* rois   = (const float*)d_in[3];
    float* out = (float*)d_out;

    unsigned short* AopM = (unsigned short*)d_ws;      // 2MB
    unsigned short* BopM = AopM + (1u << 20);          // 2MB
    unsigned short* GA   = BopM + (1u << 20);          // 2MB
    unsigned short* GB   = GA   + (1u << 20);          // 2MB

    prep_kernel<<<2176, 256, 0, stream>>>(images, logS, log1S, rois,
                                          AopM, BopM, GA, GB, out);
    crf_kernel<<<1024, 256, 0, stream>>>(AopM, BopM, GA, GB, out);
}